// Round 3
// baseline (27.541 us; speedup 1.0000x reference)
//
#include <hip/hip_runtime.h>

#define N 2048
#define BATCH 32
#define BLOCK 256
#define WAVES (BLOCK / 64)
#define I_PER_WAVE 8
#define I_PER_BLOCK (WAVES * I_PER_WAVE)   // 32 outputs per block
#define SLICES (N / I_PER_BLOCK)           // 64 blocks per batch row
#define K4 (N / 64 / 4)                    // 8 float4 per lane = full row per wave

// One wave holds the entire 2048-float row in registers (8 x float4 per lane)
// and produces 8 outputs. No LDS staging, no barriers, no max-subtraction
// (exp2 args bounded by ~|4*4|/16*log2e ~= 1.7, scale cancels in num/den).
__global__ __launch_bounds__(BLOCK, 8) void rank1_attn_kernel(
    const float* __restrict__ x, float* __restrict__ y) {
    const int bid   = blockIdx.x;
    const int b     = bid / SLICES;
    const int slice = bid % SLICES;
    const int lane  = threadIdx.x & 63;
    const int wave  = threadIdx.x >> 6;

    const float* xb = x + b * N;

    // full row -> registers, coalesced: lane l takes float4 #(l + k*64)
    float4 xr[K4];
    const float4* xb4 = reinterpret_cast<const float4*>(xb);
#pragma unroll
    for (int k = 0; k < K4; ++k) xr[k] = xb4[lane + k * 64];

    const int   ibase = slice * I_PER_BLOCK + wave * I_PER_WAVE;
    const float C     = 1.4426950408889634f / 16.0f;  // log2(e)/16

    // preload the 8 query values (uniform per wave, broadcast loads)
    float xi0 = xb[ibase + 0], xi1 = xb[ibase + 1];
    float xi2 = xb[ibase + 2], xi3 = xb[ibase + 3];
    float xi4 = xb[ibase + 4], xi5 = xb[ibase + 5];
    float xi6 = xb[ibase + 6], xi7 = xb[ibase + 7];
    float xiv[I_PER_WAVE] = {xi0, xi1, xi2, xi3, xi4, xi5, xi6, xi7};

#pragma unroll
    for (int ii = 0; ii < I_PER_WAVE; ++ii) {
        const float tl = xiv[ii] * C;
        float den0 = 0.f, num0 = 0.f, den1 = 0.f, num1 = 0.f;
#pragma unroll
        for (int k = 0; k < K4; ++k) {
            const float4 v = xr[k];
            float e0 = __builtin_amdgcn_exp2f(tl * v.x);
            float e1 = __builtin_amdgcn_exp2f(tl * v.y);
            float e2 = __builtin_amdgcn_exp2f(tl * v.z);
            float e3 = __builtin_amdgcn_exp2f(tl * v.w);
            den0 += e0; num0 = fmaf(e0, v.x, num0);
            den1 += e1; num1 = fmaf(e1, v.y, num1);
            den0 += e2; num0 = fmaf(e2, v.z, num0);
            den1 += e3; num1 = fmaf(e3, v.w, num1);
        }
        float den = den0 + den1;
        float num = num0 + num1;
        // 64-lane butterfly reduce
#pragma unroll
        for (int off = 1; off < 64; off <<= 1) {
            den += __shfl_xor(den, off);
            num += __shfl_xor(num, off);
        }
        if (lane == 0) y[b * N + ibase + ii] = num / den;
    }
}

extern "C" void kernel_launch(void* const* d_in, const int* in_sizes, int n_in,
                              void* d_out, int out_size, void* d_ws, size_t ws_size,
                              hipStream_t stream) {
    const float* x = (const float*)d_in[0];
    float* y = (float*)d_out;
    dim3 grid(BATCH * SLICES);
    dim3 block(BLOCK);
    rank1_attn_kernel<<<grid, block, 0, stream>>>(x, y);
}

// Round 4
// 21.416 us; speedup vs baseline: 1.2860x; 1.2860x over previous
//
#include <hip/hip_runtime.h>

#define N 2048
#define BATCH 32
#define BLOCK 256
#define SLICES 64                  // blocks per batch row
#define I_PER_BLOCK (N / SLICES)   // 32 output elements per block
#define SUBS 8                     // threads cooperating per output i

typedef float v2f __attribute__((ext_vector_type(2)));

// Each block: one (batch, i-slice). Stage x_b in LDS; 8 threads per output i,
// each covering 256 j's via float4. Inner math in packed-f32 (v_pk_*) pairs;
// no max-subtraction (exp2 args bounded ~|5.5^2|/16*log2e < 2.8, scale
// cancels in num/den — validated R3, absmax 4.9e-4).
__global__ __launch_bounds__(BLOCK, 8) void rank1_attn_kernel(
    const float* __restrict__ x, float* __restrict__ y) {
    __shared__ float sx[N];

    const int b     = blockIdx.x / SLICES;
    const int slice = blockIdx.x % SLICES;
    const int tid   = threadIdx.x;

    const float* xb = x + b * N;

    // ---- stage row into LDS (coalesced float4) ----
    const float4* xb4 = reinterpret_cast<const float4*>(xb);
    float4* sx4 = reinterpret_cast<float4*>(sx);
#pragma unroll
    for (int k = 0; k < 2; ++k) sx4[tid + k * BLOCK] = xb4[tid + k * BLOCK];
    __syncthreads();

    // ---- per-thread setup: SUBS threads per output i ----
    const int iLocal = tid / SUBS;      // 0..31
    const int sub    = tid % SUBS;      // 0..7
    const int i      = slice * I_PER_BLOCK + iLocal;

    const float C  = 1.4426950408889634f / 16.0f;   // log2(e)/16
    const float tl = sx[i] * C;
    const v2f  tl2 = {tl, tl};

    v2f den01 = {0.f, 0.f}, den23 = {0.f, 0.f};
    v2f num01 = {0.f, 0.f}, num23 = {0.f, 0.f};

    const float4* s4 = reinterpret_cast<const float4*>(sx);
    // j = jj*(SUBS*4) + sub*4 + {0..3}; jj in [0, 64) -> 256 j's per thread
#pragma unroll 8
    for (int jj = 0; jj < N / (SUBS * 4); ++jj) {
        float4 v = s4[jj * SUBS + sub];
        v2f v01 = {v.x, v.y};
        v2f v23 = {v.z, v.w};
        v2f a01 = tl2 * v01;            // v_pk_mul_f32
        v2f a23 = tl2 * v23;
        v2f e01, e23;
        e01.x = __builtin_amdgcn_exp2f(a01.x);
        e01.y = __builtin_amdgcn_exp2f(a01.y);
        e23.x = __builtin_amdgcn_exp2f(a23.x);
        e23.y = __builtin_amdgcn_exp2f(a23.y);
        den01 += e01;                   // v_pk_add_f32
        den23 += e23;
        num01 = e01 * v01 + num01;      // v_pk_fma_f32 (contract)
        num23 = e23 * v23 + num23;
    }
    float den = (den01.x + den01.y) + (den23.x + den23.y);
    float num = (num01.x + num01.y) + (num23.x + num23.y);

    // reduce across the 8 cooperating lanes (consecutive lanes in one wave)
    num += __shfl_xor(num, 1); den += __shfl_xor(den, 1);
    num += __shfl_xor(num, 2); den += __shfl_xor(den, 2);
    num += __shfl_xor(num, 4); den += __shfl_xor(den, 4);

    if (sub == 0) y[b * N + i] = num / den;
}

extern "C" void kernel_launch(void* const* d_in, const int* in_sizes, int n_in,
                              void* d_out, int out_size, void* d_ws, size_t ws_size,
                              hipStream_t stream) {
    const float* x = (const float*)d_in[0];
    float* y = (float*)d_out;
    dim3 grid(BATCH * SLICES);
    dim3 block(BLOCK);
    rank1_attn_kernel<<<grid, block, 0, stream>>>(x, y);
}